// Round 6
// baseline (224.027 us; speedup 1.0000x reference)
//
#include <hip/hip_runtime.h>
#include <hip/hip_fp16.h>

// Problem constants (fixed by the reference)
#define N_NODES   50000
#define N_EDGES   800000
#define IN_DIM    128
#define HID       64
#define OUT_DIM   128
#define N_GRAPHS  128

#define NBKT      196        // ceil(50000/256) dst-buckets (prefix granularity)
#define SRCSTRIDE 10240      // ushorts/bucket for padded srclist
#define CNTB      391        // count/scatter blocks: 391*2048 >= 800000
#define EPB       2048       // edges per count/scatter block

// Workspace layout in 4-byte words.
#define OFF_GSUM   0                    // float[128*64]  (zeroed by hipMemsetAsync)
#define OFF_DEG    8192                 // int[50000]     (zeroed with gsum)
#define OFF_GSTART 58192                // int[130]
#define OFF_ROWPTR 58324                // int[50000]: (pos | nchunks<<24)
#define OFF_CURSOR 108324               // int[50000] scatter cursors
#define OFF_SRCL   158324               // ushort[196*10240] = 1,003,520 words (16B-aligned)
#define OFF_HA     1161844              // fp8[50001*64] (row 50000 = zero sentinel)
#define OFF_HB     1961860              // fp8[50001*64]
#define OFF_WT     2761876              // bf16 transposed conv weights:
//   Wt1_0 @ushort 8704 (64x72); Wt2_0 @13312; Wt1_1 @17920; Wt2_1 @22528
// end = 2,775,444 words = 11.1 MB

// ---------------------------------------------------------------- helpers
typedef float v2f __attribute__((ext_vector_type(2)));
typedef float f32x4 __attribute__((ext_vector_type(4)));
typedef short bf16x8 __attribute__((ext_vector_type(8)));   // 8 bf16 in 4 VGPRs

union FragU { uint4 u; bf16x8 v; };

__device__ __forceinline__ unsigned short f2bf(float f) {   // RNE fp32->bf16
    union { float f; unsigned int u; } v; v.f = f;
    const unsigned int r = v.u + 0x7FFFu + ((v.u >> 16) & 1u);
    return (unsigned short)(r >> 16);
}

__device__ __forceinline__ void acc_fp8x8(float acc[8], const uint2 w) {
    const v2f a = __builtin_amdgcn_cvt_pk_f32_fp8(w.x, false);
    const v2f b = __builtin_amdgcn_cvt_pk_f32_fp8(w.x, true);
    const v2f c = __builtin_amdgcn_cvt_pk_f32_fp8(w.y, false);
    const v2f d = __builtin_amdgcn_cvt_pk_f32_fp8(w.y, true);
    acc[0] += a.x; acc[1] += a.y; acc[2] += b.x; acc[3] += b.y;
    acc[4] += c.x; acc[5] += c.y; acc[6] += d.x; acc[7] += d.y;
}

__device__ __forceinline__ uint2 pack_fp8x8(const float f[8]) {
    int w0 = 0, w1 = 0;
    w0 = __builtin_amdgcn_cvt_pk_fp8_f32(f[0], f[1], w0, false);
    w0 = __builtin_amdgcn_cvt_pk_fp8_f32(f[2], f[3], w0, true);
    w1 = __builtin_amdgcn_cvt_pk_fp8_f32(f[4], f[5], w1, false);
    w1 = __builtin_amdgcn_cvt_pk_fp8_f32(f[6], f[7], w1, true);
    uint2 r; r.x = (unsigned)w0; r.y = (unsigned)w1;
    return r;
}

// ================================================================ K1: degree count + gbound + wprep + proj_in
// blocks [0,391): count; [391,587): gbound; 587: wprep(+sentinels); [588,1370): proj.
// count blocks are latency-light L2 atomics; proj blocks are compute-heavy --
// co-scheduling hides the count under proj's MFMA work.
#define K1_SMEM_BYTES 34816   // proj: 17408+17408

__device__ __forceinline__ void role_count(const int* __restrict__ ei,
                                           int* __restrict__ deg, int bid) {
    const int t = threadIdx.x;
    const int base = bid * EPB;
#pragma unroll
    for (int off = 0; off < EPB; off += 1024) {
        const int e = base + off + t * 4;
        if (e + 4 <= N_EDGES) {
            const int4 d4 = *(const int4*)&ei[N_EDGES + e];   // 16B-aligned (800000%4==0)
            atomicAdd(&deg[d4.x], 1);
            atomicAdd(&deg[d4.y], 1);
            atomicAdd(&deg[d4.z], 1);
            atomicAdd(&deg[d4.w], 1);
        } else {
#pragma unroll
            for (int j = 0; j < 4; ++j)
                if (e + j < N_EDGES) atomicAdd(&deg[ei[N_EDGES + e + j]], 1);
        }
    }
}

__device__ __forceinline__ void role_gbound(const int* __restrict__ batch,
                                            int* __restrict__ gstart, int bid) {
    const int n = bid * 256 + threadIdx.x;
    if (n >= N_NODES) return;
    const int b = batch[n];
    if (n == 0) {
        for (int g = 0; g <= b; ++g) gstart[g] = 0;
    } else {
        const int p = batch[n - 1];
        for (int g = p + 1; g <= b; ++g) gstart[g] = n;
    }
    if (n == N_NODES - 1) {
        for (int g = b + 1; g <= N_GRAPHS; ++g) gstart[g] = N_NODES;
    }
}

// bf16-transpose the 4 conv weight matrices + zero the fp8 sentinel rows.
// Consumed >=2 kernels later (no intra-kernel race).
__device__ __forceinline__ void role_wprep(const float* __restrict__ W10,
                                           const float* __restrict__ W20,
                                           const float* __restrict__ W11,
                                           const float* __restrict__ W21,
                                           unsigned short* __restrict__ wtg,
                                           unsigned char* __restrict__ hA,
                                           unsigned char* __restrict__ hB) {
    const int t = threadIdx.x;
    const float* Ws[4] = {W10, W20, W11, W21};
#pragma unroll
    for (int m = 0; m < 4; ++m) {
        unsigned short* o = wtg + 8704 + m * 4608;   // [c][k], stride 72
        const float* w = Ws[m];
        for (int i = t; i < 64 * 64; i += 256) {
            const int k = i >> 6, c = i & 63;
            o[c * 72 + k] = f2bf(w[i]);
        }
    }
    if (t < 16) {   // zero sentinel row 50000 (gathered by padded chunks)
        ((unsigned int*)(hA + (size_t)N_NODES * HID))[t] = 0u;
        ((unsigned int*)(hB + (size_t)N_NODES * HID))[t] = 0u;
    }
}

// proj_in via MFMA: h = x(64x128) @ W_in(128x64) + b, fp8 out.
// W_in staged+transposed from fp32 in-block (L2-cached across 782 blocks; R3-proven).
__device__ __forceinline__ void role_proj(char* smem, const float* __restrict__ x,
                                          const float* __restrict__ Wi,
                                          const float* __restrict__ b,
                                          unsigned char* __restrict__ h8, int bid) {
    unsigned short* X16 = (unsigned short*)smem;            // 64 x 136 bf16 = 17408 B
    unsigned short* Wt  = (unsigned short*)(smem + 17408);  // 64 x 136 bf16
    float* OUT32 = (float*)smem;                            // 64 x 68 f32 (overlays X16)
    const int t = threadIdx.x;
    const int nb = bid * 64;
    for (int i = t; i < 128 * 64; i += 256) {               // transpose W_in
        const int k = i >> 6, c = i & 63;
        Wt[c * 136 + k] = f2bf(Wi[i]);
    }
    for (int i = t; i < 64 * (IN_DIM / 4); i += 256) {
        const int n = i >> 5;
        const int k4 = (i & 31) * 4;
        float4 val = make_float4(0.f, 0.f, 0.f, 0.f);
        if (nb + n < N_NODES)
            val = *(const float4*)(x + (size_t)(nb + n) * IN_DIM + k4);
        union { uint2 u; unsigned short s[4]; } pk;
        pk.s[0] = f2bf(val.x); pk.s[1] = f2bf(val.y);
        pk.s[2] = f2bf(val.z); pk.s[3] = f2bf(val.w);
        *(uint2*)&X16[n * 136 + k4] = pk.u;     // 8B-aligned (272n + 8m)
    }
    __syncthreads();

    const int l = t & 63;
    const int m0 = (t >> 6) * 16;          // wave's 16-node row block
    const int lrow = l & 15;
    const int lk = (l >> 4) * 8;
    FragU a[4];
#pragma unroll
    for (int s = 0; s < 4; ++s)
        a[s].u = *(const uint4*)&X16[(m0 + lrow) * 136 + s * 32 + lk];
    f32x4 acc[4];
#pragma unroll
    for (int n = 0; n < 4; ++n) {
        const float bv = b[n * 16 + lrow];
        acc[n] = (f32x4){bv, bv, bv, bv};
#pragma unroll
        for (int s = 0; s < 4; ++s) {
            FragU w;
            w.u = *(const uint4*)&Wt[(n * 16 + lrow) * 136 + s * 32 + lk];
            acc[n] = __builtin_amdgcn_mfma_f32_16x16x32_bf16(a[s].v, w.v, acc[n], 0, 0, 0);
        }
    }
    __syncthreads();                       // all X16/Wt fragment reads complete
#pragma unroll
    for (int n = 0; n < 4; ++n)
#pragma unroll
        for (int r = 0; r < 4; ++r)
            OUT32[(m0 + (l >> 4) * 4 + r) * 68 + n * 16 + lrow] = acc[n][r];
    __syncthreads();
    const int ln = t & 31;
    const int c0 = (t >> 5) * 8;
#pragma unroll
    for (int j = 0; j < 2; ++j) {
        const int n = nb + ln + 32 * j;
        if (n < N_NODES) {
            float f[8];
            const float* src = &OUT32[(ln + 32 * j) * 68 + c0];
            *(float4*)&f[0] = *(const float4*)&src[0];
            *(float4*)&f[4] = *(const float4*)&src[4];
            const uint2 p = pack_fp8x8(f);
            *(uint2*)(h8 + (size_t)n * HID + c0) = p;
        }
    }
}

__global__ __launch_bounds__(256) void k_front(
        const int* __restrict__ ei, const int* __restrict__ batch,
        int* __restrict__ deg, int* __restrict__ gstart,
        const float* __restrict__ x, const float* __restrict__ Wi,
        const float* __restrict__ bi, unsigned char* __restrict__ hA,
        unsigned char* __restrict__ hB,
        const float* __restrict__ W10, const float* __restrict__ W20,
        const float* __restrict__ W11, const float* __restrict__ W21,
        unsigned short* __restrict__ wtg) {
    __shared__ __attribute__((aligned(16))) char smem[K1_SMEM_BYTES];
    const int bid = blockIdx.x;
    if (bid < CNTB)              role_count(ei, deg, bid);
    else if (bid < CNTB + NBKT)  role_gbound(batch, gstart, bid - CNTB);
    else if (bid == CNTB + NBKT) role_wprep(W10, W20, W11, W21, wtg, hA, hB);
    else                         role_proj(smem, x, Wi, bi, hA, bid - (CNTB + NBKT + 1));
}

// ================================================================ K2: row layout from degrees
// Per bucket of 256 nodes: 8-pad degrees, block-scan, write rowptr2/cursor,
// sentinel-fill ONLY each node's <=7 tail slots (scatter fills the rest).
__global__ __launch_bounds__(256) void k_rows(
        const int* __restrict__ deg, int* __restrict__ rowptr2,
        int* __restrict__ cursor, unsigned short* __restrict__ srclist) {
    __shared__ int wtot[4];
    const int b = blockIdx.x;
    const int t = threadIdx.x;
    const int lane = t & 63, wv = t >> 6;
    const int node = b * 256 + t;
    const int d = (node < N_NODES) ? deg[node] : 0;
    const int p8 = (d + 7) & ~7;          // padded degree
    int incl = p8;
#pragma unroll
    for (int off = 1; off < 64; off <<= 1) {
        const int u = __shfl_up(incl, off, 64);
        if (lane >= off) incl += u;
    }
    if (lane == 63) wtot[wv] = incl;
    __syncthreads();
    int woff = 0;
#pragma unroll
    for (int i = 0; i < 4; ++i) woff += (i < wv) ? wtot[i] : 0;
    const int pos = b * SRCSTRIDE + woff + incl - p8;
    if (node < N_NODES) {
        rowptr2[node] = pos | ((p8 >> 3) << 24);
        cursor[node]  = pos;
        for (int i = d; i < p8; ++i)
            srclist[pos + i] = (unsigned short)N_NODES;   // sentinel tail
    }
}

// ================================================================ K3: edge scatter into padded srclist
__global__ __launch_bounds__(256) void k_scat(
        const int* __restrict__ ei, int* __restrict__ cursor,
        unsigned short* __restrict__ srclist) {
    const int t = threadIdx.x;
    const int base = blockIdx.x * EPB;
#pragma unroll
    for (int off = 0; off < EPB; off += 1024) {
        const int e = base + off + t * 4;
        if (e + 4 <= N_EDGES) {
            const int4 s4 = *(const int4*)&ei[e];
            const int4 d4 = *(const int4*)&ei[N_EDGES + e];
            const int p0 = atomicAdd(&cursor[d4.x], 1);
            const int p1 = atomicAdd(&cursor[d4.y], 1);
            const int p2 = atomicAdd(&cursor[d4.z], 1);
            const int p3 = atomicAdd(&cursor[d4.w], 1);
            srclist[p0] = (unsigned short)s4.x;
            srclist[p1] = (unsigned short)s4.y;
            srclist[p2] = (unsigned short)s4.z;
            srclist[p3] = (unsigned short)s4.w;
        } else {
#pragma unroll
            for (int j = 0; j < 4; ++j)
                if (e + j < N_EDGES) {
                    const int p = atomicAdd(&cursor[ei[N_EDGES + e + j]], 1);
                    srclist[p] = (unsigned short)ei[e + j];
                }
        }
    }
}

// ================================================================ fused conv: gather + MFMA 2-layer MLP (R5-proven)
#define S_AB 72   // bf16 row stride: 144 B (16B-aligned rows, 4-word bank skew)

__device__ __forceinline__ void gather8(float acc[8],
                                        const unsigned char* __restrict__ hin8,
                                        const uint4 c, const int q) {
    unsigned s[8] = {c.x & 0xFFFFu, c.x >> 16, c.y & 0xFFFFu, c.y >> 16,
                     c.z & 0xFFFFu, c.z >> 16, c.w & 0xFFFFu, c.w >> 16};
    uint2 r[8];
#pragma unroll
    for (int j = 0; j < 8; ++j)
        r[j] = *(const uint2*)(hin8 + (size_t)s[j] * HID + q * 8);
#pragma unroll
    for (int j = 0; j < 8; ++j) acc_fp8x8(acc, r[j]);
}

template<int POOL>
__global__ __launch_bounds__(256, 4) void k_conv_t(
        const unsigned char* __restrict__ hin8,
        const int* __restrict__ rowptr2, const unsigned short* __restrict__ srclist,
        const unsigned short* __restrict__ W1t_g, const float* __restrict__ b1,
        const unsigned short* __restrict__ W2t_g, const float* __restrict__ b2,
        unsigned char* __restrict__ hout8,
        const int* __restrict__ batch, float* __restrict__ gsum) {
    __shared__ __attribute__((aligned(16))) char csm[36864];
    unsigned short* A16 = (unsigned short*)csm;             // 64 x 72 bf16 = 9216
    unsigned short* H16 = (unsigned short*)(csm + 9216);    // 9216
    unsigned short* W1t = (unsigned short*)(csm + 18432);   // 9216
    unsigned short* W2t = (unsigned short*)(csm + 27648);   // 9216
    float* OUT32 = (float*)csm;                             // 64 x 68 f32 (overlays A16+H16)
    const int t = threadIdx.x;
    {   // stage both weight matrices (16B copies)
        const uint4* s1 = (const uint4*)W1t_g;
        const uint4* s2 = (const uint4*)W2t_g;
        uint4* d1 = (uint4*)W1t;
        uint4* d2 = (uint4*)W2t;
        for (int i = t; i < 576; i += 256) { d1[i] = s1[i]; d2[i] = s2[i]; }
    }

    const int nb = blockIdx.x * 64;
    const int grp = t >> 3;            // 0..31: node within pass
    const int q = t & 7;               // 8-byte chunk of the 64B row
#pragma unroll
    for (int pass = 0; pass < 2; ++pass) {
        const int nloc = pass * 32 + grp;
        const int node = nb + nloc;
        float acc[8] = {0.f, 0.f, 0.f, 0.f, 0.f, 0.f, 0.f, 0.f};
        if (node < N_NODES) {
            acc_fp8x8(acc, *(const uint2*)(hin8 + (size_t)node * HID + q * 8)); // self
            const int v = rowptr2[node];
            const int beg = v & 0xFFFFFF;
            const int ch = (int)((unsigned)v >> 24);
            if (ch) {
                uint4 idx = *(const uint4*)&srclist[beg];
                for (int i = 0; i < ch; ++i) {
                    const uint4 cur = idx;
                    if (i + 1 < ch) idx = *(const uint4*)&srclist[beg + (i + 1) * 8];
                    gather8(acc, hin8, cur, q);
                }
            }
        }
        union { uint4 u; unsigned short s[8]; } ou;
#pragma unroll
        for (int c = 0; c < 8; ++c) ou.s[c] = f2bf(acc[c]);
        *(uint4*)&A16[nloc * S_AB + q * 8] = ou.u;   // 16B store, 144B rows
    }
    __syncthreads();

    // ---- MFMA MLP: out = relu( relu(A@W1+b1) @ W2 + b2 )
    const int l = t & 63;
    const int m0 = (t >> 6) * 16;
    const int lrow = l & 15;
    const int lk = (l >> 4) * 8;

    FragU a0, a1;
    a0.u = *(const uint4*)&A16[(m0 + lrow) * S_AB + lk];
    a1.u = *(const uint4*)&A16[(m0 + lrow) * S_AB + 32 + lk];
    f32x4 acc1[4];
#pragma unroll
    for (int n = 0; n < 4; ++n) {
        const float bv = b1[n * 16 + lrow];
        acc1[n] = (f32x4){bv, bv, bv, bv};
        FragU w0, w1;
        w0.u = *(const uint4*)&W1t[(n * 16 + lrow) * S_AB + lk];
        w1.u = *(const uint4*)&W1t[(n * 16 + lrow) * S_AB + 32 + lk];
        acc1[n] = __builtin_amdgcn_mfma_f32_16x16x32_bf16(a0.v, w0.v, acc1[n], 0, 0, 0);
        acc1[n] = __builtin_amdgcn_mfma_f32_16x16x32_bf16(a1.v, w1.v, acc1[n], 0, 0, 0);
    }
    __syncthreads();                       // layer-1 A16 reads complete (H16 separate)
#pragma unroll
    for (int n = 0; n < 4; ++n)
#pragma unroll
        for (int r = 0; r < 4; ++r) {
            const int row = m0 + (l >> 4) * 4 + r;
            H16[row * S_AB + n * 16 + lrow] = f2bf(fmaxf(acc1[n][r], 0.0f));
        }
    __syncthreads();

    FragU h0, h1;
    h0.u = *(const uint4*)&H16[(m0 + lrow) * S_AB + lk];
    h1.u = *(const uint4*)&H16[(m0 + lrow) * S_AB + 32 + lk];
    f32x4 acc2[4];
#pragma unroll
    for (int n = 0; n < 4; ++n) {
        const float bv = b2[n * 16 + lrow];
        acc2[n] = (f32x4){bv, bv, bv, bv};
        FragU w0, w1;
        w0.u = *(const uint4*)&W2t[(n * 16 + lrow) * S_AB + lk];
        w1.u = *(const uint4*)&W2t[(n * 16 + lrow) * S_AB + 32 + lk];
        acc2[n] = __builtin_amdgcn_mfma_f32_16x16x32_bf16(h0.v, w0.v, acc2[n], 0, 0, 0);
        acc2[n] = __builtin_amdgcn_mfma_f32_16x16x32_bf16(h1.v, w1.v, acc2[n], 0, 0, 0);
    }
    __syncthreads();                       // all H16/A16 reads done; OUT32 overlay safe
#pragma unroll
    for (int n = 0; n < 4; ++n)
#pragma unroll
        for (int r = 0; r < 4; ++r)
            OUT32[(m0 + (l >> 4) * 4 + r) * 68 + n * 16 + lrow] = fmaxf(acc2[n][r], 0.0f);
    __syncthreads();

    // ---- epilogue in the proven (node, 8-col) mapping
    const int ln = t & 31;
    const int c0 = (t >> 5) * 8;
    if constexpr (POOL) {
        const int nlast = (nb + 64 <= N_NODES) ? nb + 63 : N_NODES - 1;
        const int g0 = batch[nb];
        const int g1 = batch[nlast];
        int myg[2];
        float f[2][8];
#pragma unroll
        for (int j = 0; j < 2; ++j) {
            const int n = nb + ln + 32 * j;
            myg[j] = (n < N_NODES) ? batch[n] : -1;
            const float* src = &OUT32[(ln + 32 * j) * 68 + c0];
            *(float4*)&f[j][0] = *(const float4*)&src[0];
            *(float4*)&f[j][4] = *(const float4*)&src[4];
        }
        for (int g = g0; g <= g1; ++g) {
#pragma unroll
            for (int j = 0; j < 2; ++j) {
#pragma unroll
                for (int c = 0; c < 8; ++c) {
                    float v = (myg[j] == g) ? f[j][c] : 0.0f;
#pragma unroll
                    for (int m = 16; m; m >>= 1) v += __shfl_xor(v, m, 64);
                    if (ln == 0) atomicAdd(&gsum[g * HID + c0 + c], v);
                }
            }
        }
    } else {
#pragma unroll
        for (int j = 0; j < 2; ++j) {
            const int n = nb + ln + 32 * j;
            if (n < N_NODES) {
                float f[8];
                const float* src = &OUT32[(ln + 32 * j) * 68 + c0];
                *(float4*)&f[0] = *(const float4*)&src[0];
                *(float4*)&f[4] = *(const float4*)&src[4];
                const uint2 p = pack_fp8x8(f);
                *(uint2*)(hout8 + (size_t)n * HID + c0) = p;
            }
        }
    }
}

// ---------------------------------------------------------------- tiny out: mean + proj_out from gsum
__global__ __launch_bounds__(128) void k_out(
        const float* __restrict__ gsum, const int* __restrict__ gstart,
        const float* __restrict__ Wo, const float* __restrict__ bo,
        float* __restrict__ out) {
    __shared__ float mean[HID];
    const int g = blockIdx.x;
    const int t = threadIdx.x;
    const int cnt = gstart[g + 1] - gstart[g];
    if (t < HID)
        mean[t] = (cnt > 0) ? gsum[g * HID + t] / (float)cnt : 0.0f;
    __syncthreads();
    float o = 0.0f;
    for (int k = 0; k < HID; ++k)
        o = fmaf(mean[k], Wo[k * OUT_DIM + t], o);
    out[g * OUT_DIM + t] = (cnt > 0) ? o + bo[t] : 0.0f;
}

// ---------------------------------------------------------------- launch
extern "C" void kernel_launch(void* const* d_in, const int* in_sizes, int n_in,
                              void* d_out, int out_size, void* d_ws, size_t ws_size,
                              hipStream_t stream) {
    const float* x     = (const float*)d_in[0];
    const int*   ei    = (const int*)d_in[1];
    const int*   batch = (const int*)d_in[2];
    const float* W_in  = (const float*)d_in[3];
    const float* b_in  = (const float*)d_in[4];
    const float* W1_0  = (const float*)d_in[5];
    const float* b1_0  = (const float*)d_in[6];
    const float* W2_0  = (const float*)d_in[7];
    const float* b2_0  = (const float*)d_in[8];
    const float* W1_1  = (const float*)d_in[9];
    const float* b1_1  = (const float*)d_in[10];
    const float* W2_1  = (const float*)d_in[11];
    const float* b2_1  = (const float*)d_in[12];
    const float* W_out = (const float*)d_in[13];
    const float* b_out = (const float*)d_in[14];
    float* out = (float*)d_out;

    unsigned int*   wsw    = (unsigned int*)d_ws;
    float*          gsum   = (float*)(wsw + OFF_GSUM);
    int*            deg    = (int*)(wsw + OFF_DEG);
    int*            gstart = (int*)(wsw + OFF_GSTART);
    int*            rowptr = (int*)(wsw + OFF_ROWPTR);
    int*            cursor = (int*)(wsw + OFF_CURSOR);
    unsigned short* srcl   = (unsigned short*)(wsw + OFF_SRCL);
    unsigned char*  hA     = (unsigned char*)(wsw + OFF_HA);
    unsigned char*  hB     = (unsigned char*)(wsw + OFF_HB);
    unsigned short* wtg    = (unsigned short*)(wsw + OFF_WT);

    unsigned short* wt10  = wtg + 8704;     // 64x72 each
    unsigned short* wt20  = wtg + 13312;
    unsigned short* wt11  = wtg + 17920;
    unsigned short* wt21  = wtg + 22528;

    const int pi_blocks = (N_NODES + 63) / 64;            // 782
    const int cv_blocks = (N_NODES + 63) / 64;            // 782
    const int k1_blocks = CNTB + NBKT + 1 + pi_blocks;    // 1370

    // zero gsum + deg in one contiguous fill (graph-capturable)
    hipMemsetAsync(gsum, 0, (N_GRAPHS * HID + N_NODES) * sizeof(int), stream);
    k_front<<<k1_blocks, 256, 0, stream>>>(ei, batch, deg, gstart,
                                           x, W_in, b_in, hA, hB,
                                           W1_0, W2_0, W1_1, W2_1, wtg);
    k_rows<<<NBKT, 256, 0, stream>>>(deg, rowptr, cursor, srcl);
    k_scat<<<CNTB, 256, 0, stream>>>(ei, cursor, srcl);
    k_conv_t<0><<<cv_blocks, 256, 0, stream>>>(hA, rowptr, srcl,
                                               wt10, b1_0, wt20, b2_0, hB,
                                               batch, gsum);
    k_conv_t<1><<<cv_blocks, 256, 0, stream>>>(hB, rowptr, srcl,
                                               wt11, b1_1, wt21, b2_1, hA,
                                               batch, gsum);
    k_out<<<N_GRAPHS, 128, 0, stream>>>(gsum, gstart, W_out, b_out, out);
}

// Round 7
// 166.440 us; speedup vs baseline: 1.3460x; 1.3460x over previous
//
#include <hip/hip_runtime.h>
#include <hip/hip_fp16.h>

// Problem constants (fixed by the reference)
#define N_NODES   50000
#define N_EDGES   800000
#define IN_DIM    128
#define HID       64
#define OUT_DIM   128
#define N_GRAPHS  128

#define NBKT      196        // ceil(50000/256) dst-buckets
#define BBLK      392        // bucket-role blocks: <=4 x 512-edge windows each
#define BSTRIDE   5120       // epairs slots/bucket (mean 4096, 16-sigma margin)
#define CAP       42         // LDS staging depth per bucket-block (mean 10.4, ~9 sigma)
#define SRCSTRIDE 10240      // ushorts/bucket for padded srclist (overlays epairs)

// Workspace layout in 4-byte words.
#define OFF_GCUR   0                    // int[196]   (zeroed by hipMemsetAsync)
#define OFF_GSUM   196                  // float[128*64] (zeroed with gcur)
#define OFF_GSTART 8388                 // int[130]
#define OFF_ROWPTR 8518                 // int[50000]: (pos | nchunks<<24)
#define OFF_EPAIRS 458520               // uint[196*5120]; padded srclist overlays it
#define OFF_HA     1462040              // fp8[50001*64] (row 50000 = zero sentinel)
#define OFF_HB     2262056              // fp8[50001*64]
#define OFF_WT     3062072              // bf16 transposed conv weights:
//   Wt1_0 @ushort 8704 (64x72); Wt2_0 @13312; Wt1_1 @17920; Wt2_1 @22528
// end = 3,075,640 words = 12.30 MB

// ---------------------------------------------------------------- helpers
typedef float v2f __attribute__((ext_vector_type(2)));
typedef float f32x4 __attribute__((ext_vector_type(4)));
typedef short bf16x8 __attribute__((ext_vector_type(8)));   // 8 bf16 in 4 VGPRs

union FragU { uint4 u; bf16x8 v; };

__device__ __forceinline__ unsigned short f2bf(float f) {   // RNE fp32->bf16
    union { float f; unsigned int u; } v; v.f = f;
    const unsigned int r = v.u + 0x7FFFu + ((v.u >> 16) & 1u);
    return (unsigned short)(r >> 16);
}

__device__ __forceinline__ void acc_fp8x8(float acc[8], const uint2 w) {
    const v2f a = __builtin_amdgcn_cvt_pk_f32_fp8(w.x, false);
    const v2f b = __builtin_amdgcn_cvt_pk_f32_fp8(w.x, true);
    const v2f c = __builtin_amdgcn_cvt_pk_f32_fp8(w.y, false);
    const v2f d = __builtin_amdgcn_cvt_pk_f32_fp8(w.y, true);
    acc[0] += a.x; acc[1] += a.y; acc[2] += b.x; acc[3] += b.y;
    acc[4] += c.x; acc[5] += c.y; acc[6] += d.x; acc[7] += d.y;
}

__device__ __forceinline__ uint2 pack_fp8x8(const float f[8]) {
    int w0 = 0, w1 = 0;
    w0 = __builtin_amdgcn_cvt_pk_fp8_f32(f[0], f[1], w0, false);
    w0 = __builtin_amdgcn_cvt_pk_fp8_f32(f[2], f[3], w0, true);
    w1 = __builtin_amdgcn_cvt_pk_fp8_f32(f[4], f[5], w1, false);
    w1 = __builtin_amdgcn_cvt_pk_fp8_f32(f[6], f[7], w1, true);
    uint2 r; r.x = (unsigned)w0; r.y = (unsigned)w1;
    return r;
}

// ================================================================ K1: bucket scatter + gbound + wprep + proj_in
// blocks [0,392): bucket; [392,588): gbound; 588: wprep(+sentinels); [589,1371): proj.
// Random-address appends stay in LDS (global atomic scatter proven 10x worse, R6).
#define K1_SMEM_BYTES 34816   // max(bucket 784+196*42*4=33712, proj 17408+17408)

__device__ __forceinline__ void role_bucket(char* smem, const int* __restrict__ ei,
                                            int* __restrict__ gcur,
                                            unsigned int* __restrict__ epairs,
                                            int bid) {
    int* lcnt = (int*)smem;                                 // NBKT words
    unsigned int* stage = (unsigned int*)(smem + NBKT * 4); // NBKT*CAP words
    const int t = threadIdx.x;
    for (int i = t; i < NBKT; i += 256) lcnt[i] = 0;
    __syncthreads();
    for (int e0 = bid * 512; e0 < N_EDGES; e0 += BBLK * 512) {
#pragma unroll
        for (int half = 0; half < 2; ++half) {
            const int e = e0 + half * 256 + t;
            if (e < N_EDGES) {
                const unsigned int src = (unsigned int)ei[e];
                const unsigned int dst = (unsigned int)ei[N_EDGES + e];
                const int b = dst >> 8;
                const unsigned int pk = src | (dst << 16);   // both < 2^16
                const int pos = atomicAdd(&lcnt[b], 1);
                if (pos < CAP) stage[b * CAP + pos] = pk;
                else {  // astronomically rare overflow: direct scattered write
                    const int gp = atomicAdd(&gcur[b], 1);
                    epairs[b * BSTRIDE + gp] = pk;
                }
            }
        }
    }
    __syncthreads();
    if (t < NBKT) {
        int n = lcnt[t]; if (n > CAP) n = CAP;
        if (n > 0) {
            const int base = atomicAdd(&gcur[t], n);
            for (int i = 0; i < n; ++i)
                epairs[t * BSTRIDE + base + i] = stage[t * CAP + i];
        }
    }
}

__device__ __forceinline__ void role_gbound(const int* __restrict__ batch,
                                            int* __restrict__ gstart, int bid) {
    const int n = bid * 256 + threadIdx.x;
    if (n >= N_NODES) return;
    const int b = batch[n];
    if (n == 0) {
        for (int g = 0; g <= b; ++g) gstart[g] = 0;
    } else {
        const int p = batch[n - 1];
        for (int g = p + 1; g <= b; ++g) gstart[g] = n;
    }
    if (n == N_NODES - 1) {
        for (int g = b + 1; g <= N_GRAPHS; ++g) gstart[g] = N_NODES;
    }
}

// bf16-transpose the 4 conv weight matrices + zero the fp8 sentinel rows.
// Consumed >=2 kernels later (no intra-kernel race).
__device__ __forceinline__ void role_wprep(const float* __restrict__ W10,
                                           const float* __restrict__ W20,
                                           const float* __restrict__ W11,
                                           const float* __restrict__ W21,
                                           unsigned short* __restrict__ wtg,
                                           unsigned char* __restrict__ hA,
                                           unsigned char* __restrict__ hB) {
    const int t = threadIdx.x;
    const float* Ws[4] = {W10, W20, W11, W21};
#pragma unroll
    for (int m = 0; m < 4; ++m) {
        unsigned short* o = wtg + 8704 + m * 4608;   // [c][k], stride 72
        const float* w = Ws[m];
        for (int i = t; i < 64 * 64; i += 256) {
            const int k = i >> 6, c = i & 63;
            o[c * 72 + k] = f2bf(w[i]);
        }
    }
    if (t < 16) {   // zero sentinel row 50000 (gathered by padded chunks)
        ((unsigned int*)(hA + (size_t)N_NODES * HID))[t] = 0u;
        ((unsigned int*)(hB + (size_t)N_NODES * HID))[t] = 0u;
    }
}

// proj_in via MFMA: h = x(64x128) @ W_in(128x64) + b, fp8 out (R3-proven).
__device__ __forceinline__ void role_proj(char* smem, const float* __restrict__ x,
                                          const float* __restrict__ Wi,
                                          const float* __restrict__ b,
                                          unsigned char* __restrict__ h8, int bid) {
    unsigned short* X16 = (unsigned short*)smem;            // 64 x 136 bf16 = 17408 B
    unsigned short* Wt  = (unsigned short*)(smem + 17408);  // 64 x 136 bf16
    float* OUT32 = (float*)smem;                            // 64 x 68 f32 (overlays X16)
    const int t = threadIdx.x;
    const int nb = bid * 64;
    for (int i = t; i < 128 * 64; i += 256) {               // transpose W_in
        const int k = i >> 6, c = i & 63;
        Wt[c * 136 + k] = f2bf(Wi[i]);
    }
    for (int i = t; i < 64 * (IN_DIM / 4); i += 256) {
        const int n = i >> 5;
        const int k4 = (i & 31) * 4;
        float4 val = make_float4(0.f, 0.f, 0.f, 0.f);
        if (nb + n < N_NODES)
            val = *(const float4*)(x + (size_t)(nb + n) * IN_DIM + k4);
        union { uint2 u; unsigned short s[4]; } pk;
        pk.s[0] = f2bf(val.x); pk.s[1] = f2bf(val.y);
        pk.s[2] = f2bf(val.z); pk.s[3] = f2bf(val.w);
        *(uint2*)&X16[n * 136 + k4] = pk.u;     // 8B-aligned (272n + 8m)
    }
    __syncthreads();

    const int l = t & 63;
    const int m0 = (t >> 6) * 16;          // wave's 16-node row block
    const int lrow = l & 15;
    const int lk = (l >> 4) * 8;
    FragU a[4];
#pragma unroll
    for (int s = 0; s < 4; ++s)
        a[s].u = *(const uint4*)&X16[(m0 + lrow) * 136 + s * 32 + lk];
    f32x4 acc[4];
#pragma unroll
    for (int n = 0; n < 4; ++n) {
        const float bv = b[n * 16 + lrow];
        acc[n] = (f32x4){bv, bv, bv, bv};
#pragma unroll
        for (int s = 0; s < 4; ++s) {
            FragU w;
            w.u = *(const uint4*)&Wt[(n * 16 + lrow) * 136 + s * 32 + lk];
            acc[n] = __builtin_amdgcn_mfma_f32_16x16x32_bf16(a[s].v, w.v, acc[n], 0, 0, 0);
        }
    }
    __syncthreads();                       // all X16/Wt fragment reads complete
#pragma unroll
    for (int n = 0; n < 4; ++n)
#pragma unroll
        for (int r = 0; r < 4; ++r)
            OUT32[(m0 + (l >> 4) * 4 + r) * 68 + n * 16 + lrow] = acc[n][r];
    __syncthreads();
    const int ln = t & 31;
    const int c0 = (t >> 5) * 8;
#pragma unroll
    for (int j = 0; j < 2; ++j) {
        const int n = nb + ln + 32 * j;
        if (n < N_NODES) {
            float f[8];
            const float* src = &OUT32[(ln + 32 * j) * 68 + c0];
            *(float4*)&f[0] = *(const float4*)&src[0];
            *(float4*)&f[4] = *(const float4*)&src[4];
            const uint2 p = pack_fp8x8(f);
            *(uint2*)(h8 + (size_t)n * HID + c0) = p;
        }
    }
}

__global__ __launch_bounds__(256) void k_bg(
        const int* __restrict__ ei, const int* __restrict__ batch,
        int* __restrict__ gcur, unsigned int* __restrict__ epairs,
        int* __restrict__ gstart,
        const float* __restrict__ x, const float* __restrict__ Wi,
        const float* __restrict__ bi, unsigned char* __restrict__ hA,
        unsigned char* __restrict__ hB,
        const float* __restrict__ W10, const float* __restrict__ W20,
        const float* __restrict__ W11, const float* __restrict__ W21,
        unsigned short* __restrict__ wtg) {
    __shared__ __attribute__((aligned(16))) char smem[K1_SMEM_BYTES];
    const int bid = blockIdx.x;
    if (bid < BBLK)              role_bucket(smem, ei, gcur, epairs, bid);
    else if (bid < BBLK + NBKT)  role_gbound(batch, gstart, bid - BBLK);
    else if (bid == BBLK + NBKT) role_wprep(W10, W20, W11, W21, wtg, hA, hB);
    else                         role_proj(smem, x, Wi, bi, hA, bid - (BBLK + NBKT + 1));
}

// ================================================================ K2: CSR build, 8-padded, overlaying epairs
// R7 changes vs R5: (1) epairs staged into LDS during the histogram pass --
// the scatter phase reads LDS instead of a second 16KB L2 pass; (2) sentinel
// prefill phase removed -- each thread fills only its node's <=7 tail slots
// (disjoint from the scatter range, so order-free); (3) ushort lsrc + uint4
// vectorized copy-out. LDS total ~38.5 KB.
__global__ __launch_bounds__(256) void k_csr(
        const int* __restrict__ gcur, const unsigned int* __restrict__ epairs,
        int* __restrict__ rowptr2, unsigned short* __restrict__ srclist) {
    __shared__ int lhist[256];
    __shared__ int lcur[256];
    __shared__ int wtot[4];
    __shared__ __attribute__((aligned(16))) unsigned int epc[BSTRIDE];     // 20.5 KB
    __shared__ __attribute__((aligned(16))) unsigned short lsrc[8192];     // 16 KB
    const int b = blockIdx.x;
    const int t = threadIdx.x;
    const int lane = t & 63, wv = t >> 6;
    lhist[t] = 0;
    __syncthreads();
    const int cnt = gcur[b];

    for (int i = t; i < cnt; i += 256) {          // hist + stage epairs in LDS
        const unsigned int u = epairs[b * BSTRIDE + i];
        epc[i] = u;
        atomicAdd(&lhist[(u >> 16) & 255], 1);
    }
    __syncthreads();

    const int d = lhist[t];
    const int p8 = (d + 7) & ~7;          // padded degree
    int incl = p8;
#pragma unroll
    for (int off = 1; off < 64; off <<= 1) {
        const int u = __shfl_up(incl, off, 64);
        if (lane >= off) incl += u;
    }
    if (lane == 63) wtot[wv] = incl;
    __syncthreads();
    int woff = 0;
#pragma unroll
    for (int i = 0; i < 4; ++i) woff += (i < wv) ? wtot[i] : 0;
    const int exclP = woff + incl - p8;
    lcur[t] = exclP;
    const int node = b * 256 + t;
    if (node < N_NODES) rowptr2[node] = (b * SRCSTRIDE + exclP) | ((p8 >> 3) << 24);
    for (int i = d; i < p8; ++i)                  // own tail sentinels only
        lsrc[exclP + i] = (unsigned short)N_NODES;
    __syncthreads();
    for (int i = t; i < cnt; i += 256) {          // scatter from LDS
        const unsigned int u = epc[i];
        const int pos = atomicAdd(&lcur[(u >> 16) & 255], 1);
        lsrc[pos] = (unsigned short)(u & 0xFFFFu);
    }
    __syncthreads();
    const int padTot = wtot[0] + wtot[1] + wtot[2] + wtot[3];   // multiple of 8
    uint4* dst = (uint4*)&srclist[b * SRCSTRIDE];               // 16B-aligned
    const uint4* src = (const uint4*)lsrc;
    for (int i = t; i < (padTot >> 3); i += 256) dst[i] = src[i];
}

// ================================================================ fused conv: gather + MFMA 2-layer MLP (R5-proven)
#define S_AB 72   // bf16 row stride: 144 B (16B-aligned rows, 4-word bank skew)

__device__ __forceinline__ void gather8(float acc[8],
                                        const unsigned char* __restrict__ hin8,
                                        const uint4 c, const int q) {
    unsigned s[8] = {c.x & 0xFFFFu, c.x >> 16, c.y & 0xFFFFu, c.y >> 16,
                     c.z & 0xFFFFu, c.z >> 16, c.w & 0xFFFFu, c.w >> 16};
    uint2 r[8];
#pragma unroll
    for (int j = 0; j < 8; ++j)
        r[j] = *(const uint2*)(hin8 + (size_t)s[j] * HID + q * 8);
#pragma unroll
    for (int j = 0; j < 8; ++j) acc_fp8x8(acc, r[j]);
}

template<int POOL>
__global__ __launch_bounds__(256, 4) void k_conv_t(
        const unsigned char* __restrict__ hin8,
        const int* __restrict__ rowptr2, const unsigned short* __restrict__ srclist,
        const unsigned short* __restrict__ W1t_g, const float* __restrict__ b1,
        const unsigned short* __restrict__ W2t_g, const float* __restrict__ b2,
        unsigned char* __restrict__ hout8,
        const int* __restrict__ batch, float* __restrict__ gsum) {
    __shared__ __attribute__((aligned(16))) char csm[36864];
    unsigned short* A16 = (unsigned short*)csm;             // 64 x 72 bf16 = 9216
    unsigned short* H16 = (unsigned short*)(csm + 9216);    // 9216
    unsigned short* W1t = (unsigned short*)(csm + 18432);   // 9216
    unsigned short* W2t = (unsigned short*)(csm + 27648);   // 9216
    float* OUT32 = (float*)csm;                             // 64 x 68 f32 (overlays A16+H16)
    const int t = threadIdx.x;
    {   // stage both weight matrices (16B copies)
        const uint4* s1 = (const uint4*)W1t_g;
        const uint4* s2 = (const uint4*)W2t_g;
        uint4* d1 = (uint4*)W1t;
        uint4* d2 = (uint4*)W2t;
        for (int i = t; i < 576; i += 256) { d1[i] = s1[i]; d2[i] = s2[i]; }
    }

    const int nb = blockIdx.x * 64;
    const int grp = t >> 3;            // 0..31: node within pass
    const int q = t & 7;               // 8-byte chunk of the 64B row
#pragma unroll
    for (int pass = 0; pass < 2; ++pass) {
        const int nloc = pass * 32 + grp;
        const int node = nb + nloc;
        float acc[8] = {0.f, 0.f, 0.f, 0.f, 0.f, 0.f, 0.f, 0.f};
        if (node < N_NODES) {
            const int v = rowptr2[node];
            acc_fp8x8(acc, *(const uint2*)(hin8 + (size_t)node * HID + q * 8)); // self
            const int beg = v & 0xFFFFFF;
            const int ch = (int)((unsigned)v >> 24);
            if (ch) {
                uint4 idx = *(const uint4*)&srclist[beg];
                for (int i = 0; i < ch; ++i) {
                    const uint4 cur = idx;
                    if (i + 1 < ch) idx = *(const uint4*)&srclist[beg + (i + 1) * 8];
                    gather8(acc, hin8, cur, q);
                }
            }
        }
        union { uint4 u; unsigned short s[8]; } ou;
#pragma unroll
        for (int c = 0; c < 8; ++c) ou.s[c] = f2bf(acc[c]);
        *(uint4*)&A16[nloc * S_AB + q * 8] = ou.u;   // 16B store, 144B rows
    }
    __syncthreads();

    // ---- MFMA MLP: out = relu( relu(A@W1+b1) @ W2 + b2 )
    const int l = t & 63;
    const int m0 = (t >> 6) * 16;
    const int lrow = l & 15;
    const int lk = (l >> 4) * 8;

    FragU a0, a1;
    a0.u = *(const uint4*)&A16[(m0 + lrow) * S_AB + lk];
    a1.u = *(const uint4*)&A16[(m0 + lrow) * S_AB + 32 + lk];
    f32x4 acc1[4];
#pragma unroll
    for (int n = 0; n < 4; ++n) {
        const float bv = b1[n * 16 + lrow];
        acc1[n] = (f32x4){bv, bv, bv, bv};
        FragU w0, w1;
        w0.u = *(const uint4*)&W1t[(n * 16 + lrow) * S_AB + lk];
        w1.u = *(const uint4*)&W1t[(n * 16 + lrow) * S_AB + 32 + lk];
        acc1[n] = __builtin_amdgcn_mfma_f32_16x16x32_bf16(a0.v, w0.v, acc1[n], 0, 0, 0);
        acc1[n] = __builtin_amdgcn_mfma_f32_16x16x32_bf16(a1.v, w1.v, acc1[n], 0, 0, 0);
    }
    __syncthreads();                       // layer-1 A16 reads complete (H16 separate)
#pragma unroll
    for (int n = 0; n < 4; ++n)
#pragma unroll
        for (int r = 0; r < 4; ++r) {
            const int row = m0 + (l >> 4) * 4 + r;
            H16[row * S_AB + n * 16 + lrow] = f2bf(fmaxf(acc1[n][r], 0.0f));
        }
    __syncthreads();

    FragU h0, h1;
    h0.u = *(const uint4*)&H16[(m0 + lrow) * S_AB + lk];
    h1.u = *(const uint4*)&H16[(m0 + lrow) * S_AB + 32 + lk];
    f32x4 acc2[4];
#pragma unroll
    for (int n = 0; n < 4; ++n) {
        const float bv = b2[n * 16 + lrow];
        acc2[n] = (f32x4){bv, bv, bv, bv};
        FragU w0, w1;
        w0.u = *(const uint4*)&W2t[(n * 16 + lrow) * S_AB + lk];
        w1.u = *(const uint4*)&W2t[(n * 16 + lrow) * S_AB + 32 + lk];
        acc2[n] = __builtin_amdgcn_mfma_f32_16x16x32_bf16(h0.v, w0.v, acc2[n], 0, 0, 0);
        acc2[n] = __builtin_amdgcn_mfma_f32_16x16x32_bf16(h1.v, w1.v, acc2[n], 0, 0, 0);
    }
    __syncthreads();                       // all H16/A16 reads done; OUT32 overlay safe
#pragma unroll
    for (int n = 0; n < 4; ++n)
#pragma unroll
        for (int r = 0; r < 4; ++r)
            OUT32[(m0 + (l >> 4) * 4 + r) * 68 + n * 16 + lrow] = fmaxf(acc2[n][r], 0.0f);
    __syncthreads();

    // ---- epilogue in the proven (node, 8-col) mapping
    const int ln = t & 31;
    const int c0 = (t >> 5) * 8;
    if constexpr (POOL) {
        const int nlast = (nb + 64 <= N_NODES) ? nb + 63 : N_NODES - 1;
        const int g0 = batch[nb];
        const int g1 = batch[nlast];
        int myg[2];
        float f[2][8];
#pragma unroll
        for (int j = 0; j < 2; ++j) {
            const int n = nb + ln + 32 * j;
            myg[j] = (n < N_NODES) ? batch[n] : -1;
            const float* src = &OUT32[(ln + 32 * j) * 68 + c0];
            *(float4*)&f[j][0] = *(const float4*)&src[0];
            *(float4*)&f[j][4] = *(const float4*)&src[4];
        }
        for (int g = g0; g <= g1; ++g) {
#pragma unroll
            for (int j = 0; j < 2; ++j) {
#pragma unroll
                for (int c = 0; c < 8; ++c) {
                    float v = (myg[j] == g) ? f[j][c] : 0.0f;
#pragma unroll
                    for (int m = 16; m; m >>= 1) v += __shfl_xor(v, m, 64);
                    if (ln == 0) atomicAdd(&gsum[g * HID + c0 + c], v);
                }
            }
        }
    } else {
#pragma unroll
        for (int j = 0; j < 2; ++j) {
            const int n = nb + ln + 32 * j;
            if (n < N_NODES) {
                float f[8];
                const float* src = &OUT32[(ln + 32 * j) * 68 + c0];
                *(float4*)&f[0] = *(const float4*)&src[0];
                *(float4*)&f[4] = *(const float4*)&src[4];
                const uint2 p = pack_fp8x8(f);
                *(uint2*)(hout8 + (size_t)n * HID + c0) = p;
            }
        }
    }
}

// ---------------------------------------------------------------- tiny out: mean + proj_out from gsum
__global__ __launch_bounds__(128) void k_out(
        const float* __restrict__ gsum, const int* __restrict__ gstart,
        const float* __restrict__ Wo, const float* __restrict__ bo,
        float* __restrict__ out) {
    __shared__ float mean[HID];
    const int g = blockIdx.x;
    const int t = threadIdx.x;
    const int cnt = gstart[g + 1] - gstart[g];
    if (t < HID)
        mean[t] = (cnt > 0) ? gsum[g * HID + t] / (float)cnt : 0.0f;
    __syncthreads();
    float o = 0.0f;
    for (int k = 0; k < HID; ++k)
        o = fmaf(mean[k], Wo[k * OUT_DIM + t], o);
    out[g * OUT_DIM + t] = (cnt > 0) ? o + bo[t] : 0.0f;
}

// ---------------------------------------------------------------- launch
extern "C" void kernel_launch(void* const* d_in, const int* in_sizes, int n_in,
                              void* d_out, int out_size, void* d_ws, size_t ws_size,
                              hipStream_t stream) {
    const float* x     = (const float*)d_in[0];
    const int*   ei    = (const int*)d_in[1];
    const int*   batch = (const int*)d_in[2];
    const float* W_in  = (const float*)d_in[3];
    const float* b_in  = (const float*)d_in[4];
    const float* W1_0  = (const float*)d_in[5];
    const float* b1_0  = (const float*)d_in[6];
    const float* W2_0  = (const float*)d_in[7];
    const float* b2_0  = (const float*)d_in[8];
    const float* W1_1  = (const float*)d_in[9];
    const float* b1_1  = (const float*)d_in[10];
    const float* W2_1  = (const float*)d_in[11];
    const float* b2_1  = (const float*)d_in[12];
    const float* W_out = (const float*)d_in[13];
    const float* b_out = (const float*)d_in[14];
    float* out = (float*)d_out;

    unsigned int*   wsw    = (unsigned int*)d_ws;
    int*            gcur   = (int*)(wsw + OFF_GCUR);
    float*          gsum   = (float*)(wsw + OFF_GSUM);
    int*            gstart = (int*)(wsw + OFF_GSTART);
    int*            rowptr = (int*)(wsw + OFF_ROWPTR);
    unsigned int*   epairs = (unsigned int*)(wsw + OFF_EPAIRS);
    unsigned short* srcl   = (unsigned short*)(wsw + OFF_EPAIRS);  // overlays epairs
    unsigned char*  hA     = (unsigned char*)(wsw + OFF_HA);
    unsigned char*  hB     = (unsigned char*)(wsw + OFF_HB);
    unsigned short* wtg    = (unsigned short*)(wsw + OFF_WT);

    unsigned short* wt10  = wtg + 8704;     // 64x72 each
    unsigned short* wt20  = wtg + 13312;
    unsigned short* wt11  = wtg + 17920;
    unsigned short* wt21  = wtg + 22528;

    const int pi_blocks = (N_NODES + 63) / 64;            // 782
    const int cv_blocks = (N_NODES + 63) / 64;            // 782
    const int bg_blocks = BBLK + NBKT + 1 + pi_blocks;    // 1371

    // zero gcur + gsum in one contiguous fill (graph-capturable)
    hipMemsetAsync(gcur, 0, (NBKT + N_GRAPHS * HID) * sizeof(int), stream);
    k_bg<<<bg_blocks, 256, 0, stream>>>(ei, batch, gcur, epairs, gstart,
                                        x, W_in, b_in, hA, hB,
                                        W1_0, W2_0, W1_1, W2_1, wtg);
    k_csr<<<NBKT, 256, 0, stream>>>(gcur, epairs, rowptr, srcl);
    k_conv_t<0><<<cv_blocks, 256, 0, stream>>>(hA, rowptr, srcl,
                                               wt10, b1_0, wt20, b2_0, hB,
                                               batch, gsum);
    k_conv_t<1><<<cv_blocks, 256, 0, stream>>>(hB, rowptr, srcl,
                                               wt11, b1_1, wt21, b2_1, hA,
                                               batch, gsum);
    k_out<<<N_GRAPHS, 128, 0, stream>>>(gsum, gstart, W_out, b_out, out);
}